// Round 1
// baseline (85.356 us; speedup 1.0000x reference)
//
#include <hip/hip_runtime.h>

#define CUTOFF 5.0f
#define NB 32

// One thread computes 4 basis values of one edge.
// 8 threads per edge; a 64-lane wave covers 8 edges and stores 1024 B contiguous.
__global__ __launch_bounds__(256) void physnet_rbf_kernel(
    const float* __restrict__ coords,   // [N_NODES, 3]
    const int*   __restrict__ recv,     // [E]
    const int*   __restrict__ send,     // [E]
    const float* __restrict__ mu,       // [32]
    const float* __restrict__ beta,     // [32]
    float*       __restrict__ out,      // [E, 32]
    int n_edges)
{
    int t  = blockIdx.x * blockDim.x + threadIdx.x;
    int e  = t >> 3;          // edge index
    int k4 = (t & 7) << 2;    // basis offset (0,4,...,28)
    if (e >= n_edges) return;

    int ir = recv[e];
    int is = send[e];

    const float* cr = coords + (size_t)ir * 3;
    const float* cs = coords + (size_t)is * 3;
    float dx = cr[0] - cs[0];
    float dy = cr[1] - cs[1];
    float dz = cr[2] - cs[2];
    float r  = sqrtf(dx * dx + dy * dy + dz * dz);

    // polynomial cutoff phi(u), u = r / cutoff  (no clamp in reference!)
    float u   = r * (1.0f / CUTOFF);
    float u3  = u * u * u;
    float phi = 1.0f + u3 * (-10.0f + u * (15.0f - 6.0f * u));

    float er = __expf(-r);

    float4 m = *reinterpret_cast<const float4*>(mu + k4);
    float4 b = *reinterpret_cast<const float4*>(beta + k4);

    float4 o;
    float d0 = er - m.x; o.x = __expf(-b.x * d0 * d0) * phi;
    float d1 = er - m.y; o.y = __expf(-b.y * d1 * d1) * phi;
    float d2 = er - m.z; o.z = __expf(-b.z * d2 * d2) * phi;
    float d3 = er - m.w; o.w = __expf(-b.w * d3 * d3) * phi;

    *reinterpret_cast<float4*>(out + (size_t)e * NB + k4) = o;
}

extern "C" void kernel_launch(void* const* d_in, const int* in_sizes, int n_in,
                              void* d_out, int out_size, void* d_ws, size_t ws_size,
                              hipStream_t stream) {
    const float* coords = (const float*)d_in[0];
    const int*   recv   = (const int*)d_in[1];
    const int*   send   = (const int*)d_in[2];
    const float* mu     = (const float*)d_in[3];
    const float* beta   = (const float*)d_in[4];
    float*       out    = (float*)d_out;

    int n_edges = in_sizes[1];           // receivers flat count = E
    int n_threads = n_edges * 8;         // 8 threads per edge (4 basis each)
    int block = 256;
    int grid = (n_threads + block - 1) / block;

    physnet_rbf_kernel<<<grid, block, 0, stream>>>(coords, recv, send, mu, beta,
                                                   out, n_edges);
}

// Round 3
// 51.369 us; speedup vs baseline: 1.6616x; 1.6616x over previous
//
#include <hip/hip_runtime.h>

#define CUTOFF 5.0f
#define NB 32

typedef float f32x4 __attribute__((ext_vector_type(4)));

// Wave-cooperative: lanes 0-7 compute per-edge scalars (r, phi, exp(-r)) for
// the wave's 8 edges, broadcast via __shfl, then all 64 lanes compute 4 basis
// values each and store one float4 -> 1024 B contiguous per wave.
__global__ __launch_bounds__(256) void physnet_rbf_kernel(
    const float* __restrict__ coords,   // [N_NODES, 3]
    const int*   __restrict__ recv,     // [E]
    const int*   __restrict__ send,     // [E]
    const float* __restrict__ mu,       // [32]
    const float* __restrict__ beta,     // [32]
    float*       __restrict__ out,      // [E, 32]
    int n_edges)
{
    int t    = blockIdx.x * blockDim.x + threadIdx.x;
    int lane = threadIdx.x & 63;
    int ebase = (t >> 6) * 8;           // first edge of this wave's 8

    float er = 0.0f, phi = 0.0f;
    if (lane < 8) {
        int e = ebase + lane;
        if (e < n_edges) {
            int ir = recv[e];
            int is = send[e];
            const float* cr = coords + (size_t)ir * 3;
            const float* cs = coords + (size_t)is * 3;
            float dx = cr[0] - cs[0];
            float dy = cr[1] - cs[1];
            float dz = cr[2] - cs[2];
            float r  = sqrtf(dx * dx + dy * dy + dz * dz);
            float u  = r * (1.0f / CUTOFF);
            float u3 = u * u * u;
            phi = 1.0f + u3 * (-10.0f + u * (15.0f - 6.0f * u));
            er  = __expf(-r);
        }
    }
    // broadcast edge (lane>>3)'s scalars from lane (lane>>3)
    int sub = lane >> 3;
    er  = __shfl(er,  sub);
    phi = __shfl(phi, sub);

    int e = ebase + sub;
    if (e >= n_edges) return;

    int k4 = (lane & 7) << 2;           // basis offset 0,4,...,28
    float4 m = *reinterpret_cast<const float4*>(mu + k4);
    float4 b = *reinterpret_cast<const float4*>(beta + k4);

    f32x4 o;
    float d0 = er - m.x; o.x = __expf(-b.x * d0 * d0) * phi;
    float d1 = er - m.y; o.y = __expf(-b.y * d1 * d1) * phi;
    float d2 = er - m.z; o.z = __expf(-b.z * d2 * d2) * phi;
    float d3 = er - m.w; o.w = __expf(-b.w * d3 * d3) * phi;

    // streaming store: don't pollute L2 (keep it for the coord gather table)
    __builtin_nontemporal_store(o, reinterpret_cast<f32x4*>(out + (size_t)e * NB + k4));
}

extern "C" void kernel_launch(void* const* d_in, const int* in_sizes, int n_in,
                              void* d_out, int out_size, void* d_ws, size_t ws_size,
                              hipStream_t stream) {
    const float* coords = (const float*)d_in[0];
    const int*   recv   = (const int*)d_in[1];
    const int*   send   = (const int*)d_in[2];
    const float* mu     = (const float*)d_in[3];
    const float* beta   = (const float*)d_in[4];
    float*       out    = (float*)d_out;

    int n_edges = in_sizes[1];           // receivers flat count = E
    long long n_threads = (long long)n_edges * 8;  // 8 lanes per edge
    int block = 256;
    long long grid = (n_threads + block - 1) / block;

    physnet_rbf_kernel<<<(int)grid, block, 0, stream>>>(coords, recv, send, mu, beta,
                                                        out, n_edges);
}